// Round 1
// baseline (37.821 us; speedup 1.0000x reference)
//
#include <hip/hip_runtime.h>
#include <math.h>

#define N 512
#define D 128
#define TPB 256

__global__ __launch_bounds__(TPB) void rnc_rows(const float* __restrict__ feat,
                                                const float* __restrict__ labels,
                                                float* __restrict__ row_out) {
    const int i = blockIdx.x;     // row
    const int tid = threadIdx.x;

    __shared__ float  fI[D];      // feature row i
    __shared__ float2 ldev[N];    // .x = label diff, .y = exp(logit - max)
    __shared__ float  lg[N];      // logits (full row, incl. diagonal = 0)
    __shared__ float  red[TPB / 64];

    // stage feature row i (128 floats = 32 float4)
    if (tid < D / 4) {
        ((float4*)fI)[tid] = ((const float4*)(feat + (size_t)i * D))[tid];
    }
    const float li0 = labels[(i & 255) * 2 + 0];
    const float li1 = labels[(i & 255) * 2 + 1];
    __syncthreads();

    // ---- phase 1: logits + label diffs, 2 columns per thread ----
    for (int j = tid; j < N; j += TPB) {
        const float4* fj = (const float4*)(feat + (size_t)j * D);
        float s = 0.f;
#pragma unroll
        for (int q = 0; q < D / 4; ++q) {
            float4 v = fj[q];
            float4 u = ((const float4*)fI)[q];
            float d0 = u.x - v.x, d1 = u.y - v.y, d2 = u.z - v.z, d3 = u.w - v.w;
            s = fmaf(d0, d0, s); s = fmaf(d1, d1, s);
            s = fmaf(d2, d2, s); s = fmaf(d3, d3, s);
        }
        float l2 = (s > 0.f) ? sqrtf(s) : 0.f;   // safe_l2: diagonal -> 0
        lg[j] = -0.5f * l2;                       // / TEMPERATURE (=2)
        float lj0 = labels[(j & 255) * 2 + 0];
        float lj1 = labels[(j & 255) * 2 + 1];
        ldev[j].x = fabsf(li0 - lj0) + fabsf(li1 - lj1);
    }
    __syncthreads();

    // ---- phase 2: row max over j != i ----
    float m = -INFINITY;
    for (int j = tid; j < N; j += TPB)
        if (j != i) m = fmaxf(m, lg[j]);
#pragma unroll
    for (int off = 32; off > 0; off >>= 1)
        m = fmaxf(m, __shfl_down(m, off, 64));
    if ((tid & 63) == 0) red[tid >> 6] = m;
    __syncthreads();
    if (tid == 0) {
        float mm = red[0];
        for (int w = 1; w < TPB / 64; ++w) mm = fmaxf(mm, red[w]);
        red[0] = mm;
    }
    __syncthreads();
    m = red[0];
    __syncthreads();           // red will be reused below

    // exp values; e[i] = 0 excludes the diagonal from every denom
    for (int j = tid; j < N; j += TPB) {
        ldev[j].y = (j == i) ? 0.f : __expf(lg[j] - m);
    }
    __syncthreads();

    // ---- phase 3: denominators; each thread owns k0 = tid, k1 = tid+TPB ----
    const int k0 = tid, k1 = tid + TPB;
    const float ldk0 = ldev[k0].x;
    const float ldk1 = ldev[k1].x;
    float den0 = 0.f, den1 = 0.f;
#pragma unroll 4
    for (int j = 0; j < N; ++j) {
        float2 le = ldev[j];   // same address across all lanes -> LDS broadcast
        den0 += (le.x >= ldk0) ? le.y : 0.f;
        den1 += (le.x >= ldk1) ? le.y : 0.f;
    }
    float part = 0.f;
    if (k0 != i) part += (lg[k0] - m) - __logf(den0);
    if (k1 != i) part += (lg[k1] - m) - __logf(den1);

    // block reduce part -> row_out[i]
#pragma unroll
    for (int off = 32; off > 0; off >>= 1)
        part += __shfl_down(part, off, 64);
    if ((tid & 63) == 0) red[tid >> 6] = part;
    __syncthreads();
    if (tid == 0) {
        float s = 0.f;
        for (int w = 0; w < TPB / 64; ++w) s += red[w];
        row_out[i] = s;
    }
}

__global__ __launch_bounds__(256) void rnc_reduce(const float* __restrict__ row_out,
                                                  float* __restrict__ out) {
    const int tid = threadIdx.x;
    double s = 0.0;
    for (int j = tid; j < N; j += 256) s += (double)row_out[j];
#pragma unroll
    for (int off = 32; off > 0; off >>= 1)
        s += __shfl_down(s, off, 64);
    __shared__ double sd[4];
    if ((tid & 63) == 0) sd[tid >> 6] = s;
    __syncthreads();
    if (tid == 0) {
        double t = sd[0] + sd[1] + sd[2] + sd[3];
        out[0] = (float)(-t / ((double)N * (double)(N - 1)));
    }
}

extern "C" void kernel_launch(void* const* d_in, const int* in_sizes, int n_in,
                              void* d_out, int out_size, void* d_ws, size_t ws_size,
                              hipStream_t stream) {
    const float* feat   = (const float*)d_in[0];   // [512,128] f32
    const float* labels = (const float*)d_in[1];   // [256,2]  f32
    float* out     = (float*)d_out;                // scalar
    float* row_out = (float*)d_ws;                 // 512 floats scratch

    rnc_rows<<<N, TPB, 0, stream>>>(feat, labels, row_out);
    rnc_reduce<<<1, 256, 0, stream>>>(row_out, out);
}

// Round 2
// 36.437 us; speedup vs baseline: 1.0380x; 1.0380x over previous
//
#include <hip/hip_runtime.h>
#include <math.h>

#define N 512
#define D 128
#define TPB 512

__global__ __launch_bounds__(TPB, 4) void rnc_rows(const float* __restrict__ feat,
                                                   const float* __restrict__ labels,
                                                   float* __restrict__ row_out) {
    const int i = blockIdx.x;     // row
    const int tid = threadIdx.x;  // owns column/k = tid

    __shared__ alignas(16) float fI[D];        // feature row i
    __shared__ alignas(16) float lds_ld[N];    // label diffs
    __shared__ alignas(16) float lds_ev[N];    // exp(logit - max), 0 at diagonal
    __shared__ alignas(16) float lds_lg[N];    // logits
    __shared__ float red[TPB / 64];

    // stage feature row i (128 floats = 32 float4)
    if (tid < D / 4) {
        ((float4*)fI)[tid] = ((const float4*)(feat + (size_t)i * D))[tid];
    }
    const float li0 = labels[(i & 255) * 2 + 0];
    const float li1 = labels[(i & 255) * 2 + 1];
    __syncthreads();

    // ---- phase 1: logit + label diff, one column per thread ----
    {
        const int j = tid;
        const float4* fj = (const float4*)(feat + (size_t)j * D);
        float s0 = 0.f, s1 = 0.f;
#pragma unroll
        for (int q = 0; q < D / 4; q += 2) {
            float4 v0 = fj[q],     u0 = ((const float4*)fI)[q];
            float4 v1 = fj[q + 1], u1 = ((const float4*)fI)[q + 1];
            float a0 = u0.x - v0.x, a1 = u0.y - v0.y, a2 = u0.z - v0.z, a3 = u0.w - v0.w;
            float b0 = u1.x - v1.x, b1 = u1.y - v1.y, b2 = u1.z - v1.z, b3 = u1.w - v1.w;
            s0 = fmaf(a0, a0, s0); s0 = fmaf(a1, a1, s0);
            s0 = fmaf(a2, a2, s0); s0 = fmaf(a3, a3, s0);
            s1 = fmaf(b0, b0, s1); s1 = fmaf(b1, b1, s1);
            s1 = fmaf(b2, b2, s1); s1 = fmaf(b3, b3, s1);
        }
        float s = s0 + s1;
        float l2 = (s > 0.f) ? sqrtf(s) : 0.f;   // safe_l2: diagonal -> 0
        lds_lg[j] = -0.5f * l2;                  // / TEMPERATURE (=2)
        float lj0 = labels[(j & 255) * 2 + 0];
        float lj1 = labels[(j & 255) * 2 + 1];
        lds_ld[j] = fabsf(li0 - lj0) + fabsf(li1 - lj1);
    }
    __syncthreads();

    // ---- phase 2: row max over j != i ----
    float m = (tid == i) ? -INFINITY : lds_lg[tid];
#pragma unroll
    for (int off = 32; off > 0; off >>= 1)
        m = fmaxf(m, __shfl_down(m, off, 64));
    if ((tid & 63) == 0) red[tid >> 6] = m;
    __syncthreads();
    if (tid == 0) {
        float mm = red[0];
#pragma unroll
        for (int w = 1; w < TPB / 64; ++w) mm = fmaxf(mm, red[w]);
        red[0] = mm;
    }
    __syncthreads();
    m = red[0];

    // exp values; ev[i] = 0 excludes the diagonal from every denom
    lds_ev[tid] = (tid == i) ? 0.f : __expf(lds_lg[tid] - m);
    __syncthreads();   // also makes red[] safe to reuse below

    // ---- phase 3: denominator for k = tid ----
    const float ldk = lds_ld[tid];
    const float4* ld4 = (const float4*)lds_ld;
    const float4* ev4 = (const float4*)lds_ev;
    float d0 = 0.f, d1 = 0.f, d2 = 0.f, d3 = 0.f;
#pragma unroll 8
    for (int q = 0; q < N / 4; ++q) {
        float4 a = ld4[q];   // wave-uniform address -> LDS broadcast
        float4 b = ev4[q];
        d0 += (a.x >= ldk) ? b.x : 0.f;
        d1 += (a.y >= ldk) ? b.y : 0.f;
        d2 += (a.z >= ldk) ? b.z : 0.f;
        d3 += (a.w >= ldk) ? b.w : 0.f;
    }
    float den = (d0 + d1) + (d2 + d3);
    float part = (tid != i) ? (lds_lg[tid] - m) - __logf(den) : 0.f;

    // block reduce part -> row_out[i]
#pragma unroll
    for (int off = 32; off > 0; off >>= 1)
        part += __shfl_down(part, off, 64);
    if ((tid & 63) == 0) red[tid >> 6] = part;
    __syncthreads();
    if (tid == 0) {
        float s = 0.f;
#pragma unroll
        for (int w = 0; w < TPB / 64; ++w) s += red[w];
        row_out[i] = s;
    }
}

__global__ __launch_bounds__(256) void rnc_reduce(const float* __restrict__ row_out,
                                                  float* __restrict__ out) {
    const int tid = threadIdx.x;
    double s = 0.0;
    for (int j = tid; j < N; j += 256) s += (double)row_out[j];
#pragma unroll
    for (int off = 32; off > 0; off >>= 1)
        s += __shfl_down(s, off, 64);
    __shared__ double sd[4];
    if ((tid & 63) == 0) sd[tid >> 6] = s;
    __syncthreads();
    if (tid == 0) {
        double t = sd[0] + sd[1] + sd[2] + sd[3];
        out[0] = (float)(-t / ((double)N * (double)(N - 1)));
    }
}

extern "C" void kernel_launch(void* const* d_in, const int* in_sizes, int n_in,
                              void* d_out, int out_size, void* d_ws, size_t ws_size,
                              hipStream_t stream) {
    const float* feat   = (const float*)d_in[0];   // [512,128] f32
    const float* labels = (const float*)d_in[1];   // [256,2]  f32
    float* out     = (float*)d_out;                // scalar
    float* row_out = (float*)d_ws;                 // 512 floats scratch

    rnc_rows<<<N, TPB, 0, stream>>>(feat, labels, row_out);
    rnc_reduce<<<1, 256, 0, stream>>>(row_out, out);
}

// Round 3
// 26.790 us; speedup vs baseline: 1.4117x; 1.3601x over previous
//
#include <hip/hip_runtime.h>
#include <math.h>

#define N 512
#define C 256          // distinct label-diff classes per row (labels repeat: j and j+256 identical)
#define D 128

// ---------------- K1: all-pairs logits lg[i][j] = -0.5 * ||fi - fj|| ----------------
// 16x16 tile grid of 32x32 tiles; each thread computes a 2x2 micro-tile.
// feat is 256KB -> L2/L3 resident; A-reads broadcast across 16 lanes, B-reads 16 lines/instr.
__global__ __launch_bounds__(256) void k1_logits(const float* __restrict__ feat,
                                                 float* __restrict__ lg) {
    const int tid = threadIdx.x;
    const int i0 = (blockIdx.x >> 4) << 5;
    const int j0 = (blockIdx.x & 15) << 5;
    const int ty = tid >> 4, tx = tid & 15;
    const int i = i0 + ty * 2;
    const int j = j0 + tx * 2;

    const float4* A0 = (const float4*)(feat + (size_t)i * D);
    const float4* A1 = A0 + D / 4;
    const float4* B0 = (const float4*)(feat + (size_t)j * D);
    const float4* B1 = B0 + D / 4;

    float s00 = 0.f, s01 = 0.f, s10 = 0.f, s11 = 0.f;
#pragma unroll 4
    for (int q = 0; q < D / 4; ++q) {
        float4 a0 = A0[q], a1 = A1[q], b0 = B0[q], b1 = B1[q];
        float t;
        t = a0.x - b0.x; s00 = fmaf(t, t, s00);
        t = a0.y - b0.y; s00 = fmaf(t, t, s00);
        t = a0.z - b0.z; s00 = fmaf(t, t, s00);
        t = a0.w - b0.w; s00 = fmaf(t, t, s00);
        t = a0.x - b1.x; s01 = fmaf(t, t, s01);
        t = a0.y - b1.y; s01 = fmaf(t, t, s01);
        t = a0.z - b1.z; s01 = fmaf(t, t, s01);
        t = a0.w - b1.w; s01 = fmaf(t, t, s01);
        t = a1.x - b0.x; s10 = fmaf(t, t, s10);
        t = a1.y - b0.y; s10 = fmaf(t, t, s10);
        t = a1.z - b0.z; s10 = fmaf(t, t, s10);
        t = a1.w - b0.w; s10 = fmaf(t, t, s10);
        t = a1.x - b1.x; s11 = fmaf(t, t, s11);
        t = a1.y - b1.y; s11 = fmaf(t, t, s11);
        t = a1.z - b1.z; s11 = fmaf(t, t, s11);
        t = a1.w - b1.w; s11 = fmaf(t, t, s11);
    }
    // safe_l2: s==0 (diagonal: identical rows) -> exactly 0
    float l00 = (s00 > 0.f) ? -0.5f * sqrtf(s00) : 0.f;
    float l01 = (s01 > 0.f) ? -0.5f * sqrtf(s01) : 0.f;
    float l10 = (s10 > 0.f) ? -0.5f * sqrtf(s10) : 0.f;
    float l11 = (s11 > 0.f) ? -0.5f * sqrtf(s11) : 0.f;

    float2* r0 = (float2*)(lg + (size_t)i * N + j);
    float2* r1 = (float2*)(lg + (size_t)(i + 1) * N + j);
    *r0 = make_float2(l00, l01);
    *r1 = make_float2(l10, l11);
}

// ---------------- K2: per-row max, exp, class-combine ----------------
// block = row i, thread = class c (0..255). Writes ld2[i][c], evs[i][c], rowsum[i].
__global__ __launch_bounds__(256) void k2_row(const float* __restrict__ lg,
                                              const float* __restrict__ labels,
                                              float* __restrict__ ld2,
                                              float* __restrict__ evs,
                                              float* __restrict__ rowsum) {
    const int i = blockIdx.x;
    const int c = threadIdx.x;

    const float la = lg[(size_t)i * N + c];
    const float lb = lg[(size_t)i * N + c + 256];

    // row max over j != i  (lg[i][i] == 0 must be excluded)
    float m = -1e30f;
    if (c != i) m = la;                       // only possible exclusion: c == i (i < 256)
    if (c + 256 != i) m = fmaxf(m, lb);       // or c+256 == i (i >= 256)
    __shared__ float redm[4];
#pragma unroll
    for (int off = 32; off > 0; off >>= 1) m = fmaxf(m, __shfl_xor(m, off, 64));
    if ((c & 63) == 0) redm[c >> 6] = m;
    __syncthreads();
    m = fmaxf(fmaxf(redm[0], redm[1]), fmaxf(redm[2], redm[3]));

    // exp values; diagonal forced to 0 so it drops out of every denominator
    float ea = (c == i) ? 0.f : __expf(la - m);
    float eb = (c + 256 == i) ? 0.f : __expf(lb - m);
    evs[(size_t)i * C + c] = ea + eb;

    // label diff per class (bitwise identical to reference's f32 math)
    const float2 lc = ((const float2*)labels)[c];
    const float2 li = ((const float2*)labels)[i & 255];
    ld2[(size_t)i * C + c] = fabsf(li.x - lc.x) + fabsf(li.y - lc.y);

    // rowsum = sum_{k != i} (lg_k - m) = (sum over all k of lg_k) - 511*m   (lg_i == 0)
    float s = la + lb;
    __shared__ float reds[4];
#pragma unroll
    for (int off = 32; off > 0; off >>= 1) s += __shfl_xor(s, off, 64);
    if ((c & 63) == 0) reds[c >> 6] = s;
    __syncthreads();
    if (c == 0) rowsum[i] = (reds[0] + reds[1] + reds[2] + reds[3]) - 511.f * m;
}

// ---------------- K3: class denominators + per-row loss ----------------
// block = row i, thread = class c. Inner loop reads wave-uniform global addresses
// (s_load / single-line L1 broadcast — no LDS traffic).
__global__ __launch_bounds__(256) void k3_den(const float* __restrict__ ld2,
                                              const float* __restrict__ evs,
                                              const float* __restrict__ rowsum,
                                              float* __restrict__ rowout) {
    const int i = blockIdx.x;
    const int c = threadIdx.x;
    const float4* a4 = (const float4*)(ld2 + (size_t)i * C);
    const float4* b4 = (const float4*)(evs + (size_t)i * C);
    const float ldk = ld2[(size_t)i * C + c];

    float d0 = 0.f, d1 = 0.f, d2 = 0.f, d3 = 0.f;
#pragma unroll 8
    for (int q = 0; q < C / 4; ++q) {
        float4 a = a4[q];   // wave-uniform address
        float4 b = b4[q];
        d0 += (a.x >= ldk) ? b.x : 0.f;
        d1 += (a.y >= ldk) ? b.y : 0.f;
        d2 += (a.z >= ldk) ? b.z : 0.f;
        d3 += (a.w >= ldk) ? b.w : 0.f;
    }
    const float lden = __logf((d0 + d1) + (d2 + d3));

    // rowout[i] = rowsum[i] - (2*sum_c log den_c - log den_{class(i)})
    __shared__ float red[4];
    __shared__ float lci;
    if (c == (i & 255)) lci = lden;     // class(i) has ld2 == 0 -> den == total ev sum
    float s = lden;
#pragma unroll
    for (int off = 32; off > 0; off >>= 1) s += __shfl_xor(s, off, 64);
    if ((c & 63) == 0) red[c >> 6] = s;
    __syncthreads();
    if (c == 0) {
        float tot = red[0] + red[1] + red[2] + red[3];
        rowout[i] = rowsum[i] - (2.f * tot - lci);
    }
}

// ---------------- K4: final reduction ----------------
__global__ __launch_bounds__(256) void k4_reduce(const float* __restrict__ rowout,
                                                 float* __restrict__ out) {
    const int tid = threadIdx.x;
    double s = 0.0;
    for (int j = tid; j < N; j += 256) s += (double)rowout[j];
#pragma unroll
    for (int off = 32; off > 0; off >>= 1) s += __shfl_down(s, off, 64);
    __shared__ double sd[4];
    if ((tid & 63) == 0) sd[tid >> 6] = s;
    __syncthreads();
    if (tid == 0) {
        double t = sd[0] + sd[1] + sd[2] + sd[3];
        out[0] = (float)(-t / ((double)N * (double)(N - 1)));
    }
}

extern "C" void kernel_launch(void* const* d_in, const int* in_sizes, int n_in,
                              void* d_out, int out_size, void* d_ws, size_t ws_size,
                              hipStream_t stream) {
    const float* feat   = (const float*)d_in[0];   // [512,128] f32
    const float* labels = (const float*)d_in[1];   // [256,2]  f32
    float* out = (float*)d_out;

    float* lg     = (float*)d_ws;                  // N*N
    float* ld2    = lg + (size_t)N * N;            // N*C
    float* evs    = ld2 + (size_t)N * C;           // N*C
    float* rowsum = evs + (size_t)N * C;           // N
    float* rowout = rowsum + N;                    // N

    k1_logits<<<256, 256, 0, stream>>>(feat, lg);
    k2_row  <<<N,   256, 0, stream>>>(lg, labels, ld2, evs, rowsum);
    k3_den  <<<N,   256, 0, stream>>>(ld2, evs, rowsum, rowout);
    k4_reduce<<<1,  256, 0, stream>>>(rowout, out);
}

// Round 4
// 20.621 us; speedup vs baseline: 1.8341x; 1.2992x over previous
//
#include <hip/hip_runtime.h>
#include <math.h>

#define N 512
#define C 256          // distinct label-diff classes per row (labels repeat)
#define D 128

// ---------------- K1: all-pairs logits via LDS-staged 32x32 tiles ----------------
// grid 256 = 16x16 tiles. Block stages A(32 rows) and B(32 cols) of feat in LDS
// with an XOR swizzle (T2 pattern) so fragment reads are conflict-free.
// Thread = 2x2 micro-tile: 32 VALU per 4 ds_read_b128 -> VALU-bound.
__global__ __launch_bounds__(256) void k1_logits(const float* __restrict__ feat,
                                                 float* __restrict__ lg) {
    const int tid = threadIdx.x;
    const int row0 = (blockIdx.x >> 4) << 5;
    const int col0 = (blockIdx.x & 15) << 5;

    __shared__ float4 As[32][32];   // [row][swizzled q]
    __shared__ float4 Bs[32][32];

    const float4* f4 = (const float4*)feat;   // [512][32]
    {
        const int r = tid >> 5, c4 = tid & 31;          // 8 rows per pass
#pragma unroll
        for (int p = 0; p < 4; ++p) {
            const int rr = r + p * 8;
            const int sc = c4 ^ ((rr >> 1) & 7);
            As[rr][sc] = f4[(size_t)(row0 + rr) * 32 + c4];
            Bs[rr][sc] = f4[(size_t)(col0 + rr) * 32 + c4];
        }
    }
    __syncthreads();

    const int ty = tid >> 4, tx = tid & 15;
    const int r0 = 2 * ty, r1 = 2 * ty + 1;
    const int c0 = 2 * tx, c1 = 2 * tx + 1;
    const int sa = ty & 7, sb = tx & 7;

    float s00 = 0.f, s01 = 0.f, s10 = 0.f, s11 = 0.f;
#pragma unroll 8
    for (int q = 0; q < 32; ++q) {
        float4 a0 = As[r0][q ^ sa];
        float4 a1 = As[r1][q ^ sa];
        float4 b0 = Bs[c0][q ^ sb];
        float4 b1 = Bs[c1][q ^ sb];
        float t;
        t = a0.x - b0.x; s00 = fmaf(t, t, s00);
        t = a0.y - b0.y; s00 = fmaf(t, t, s00);
        t = a0.z - b0.z; s00 = fmaf(t, t, s00);
        t = a0.w - b0.w; s00 = fmaf(t, t, s00);
        t = a0.x - b1.x; s01 = fmaf(t, t, s01);
        t = a0.y - b1.y; s01 = fmaf(t, t, s01);
        t = a0.z - b1.z; s01 = fmaf(t, t, s01);
        t = a0.w - b1.w; s01 = fmaf(t, t, s01);
        t = a1.x - b0.x; s10 = fmaf(t, t, s10);
        t = a1.y - b0.y; s10 = fmaf(t, t, s10);
        t = a1.z - b0.z; s10 = fmaf(t, t, s10);
        t = a1.w - b0.w; s10 = fmaf(t, t, s10);
        t = a1.x - b1.x; s11 = fmaf(t, t, s11);
        t = a1.y - b1.y; s11 = fmaf(t, t, s11);
        t = a1.z - b1.z; s11 = fmaf(t, t, s11);
        t = a1.w - b1.w; s11 = fmaf(t, t, s11);
    }
    // safe_l2: identical rows give s == 0 exactly -> logit 0 (diagonal)
    float l00 = (s00 > 0.f) ? -0.5f * sqrtf(s00) : 0.f;
    float l01 = (s01 > 0.f) ? -0.5f * sqrtf(s01) : 0.f;
    float l10 = (s10 > 0.f) ? -0.5f * sqrtf(s10) : 0.f;
    float l11 = (s11 > 0.f) ? -0.5f * sqrtf(s11) : 0.f;

    *(float2*)(lg + (size_t)(row0 + r0) * N + col0 + c0) = make_float2(l00, l01);
    *(float2*)(lg + (size_t)(row0 + r1) * N + col0 + c0) = make_float2(l10, l11);
}

// ---------------- K2: per-row max, exp, class-combine ----------------
__global__ __launch_bounds__(256) void k2_row(const float* __restrict__ lg,
                                              const float* __restrict__ labels,
                                              float* __restrict__ ld2,
                                              float* __restrict__ evs,
                                              float* __restrict__ rowsum) {
    const int i = blockIdx.x;
    const int c = threadIdx.x;

    const float la = lg[(size_t)i * N + c];
    const float lb = lg[(size_t)i * N + c + 256];

    // row max over j != i (lg[i][i] == 0 excluded)
    float m = -1e30f;
    if (c != i) m = la;
    if (c + 256 != i) m = fmaxf(m, lb);
    __shared__ float redm[4];
#pragma unroll
    for (int off = 32; off > 0; off >>= 1) m = fmaxf(m, __shfl_xor(m, off, 64));
    if ((c & 63) == 0) redm[c >> 6] = m;
    __syncthreads();
    m = fmaxf(fmaxf(redm[0], redm[1]), fmaxf(redm[2], redm[3]));

    // exp values; diagonal forced to 0 drops it from every denominator
    float ea = (c == i) ? 0.f : __expf(la - m);
    float eb = (c + 256 == i) ? 0.f : __expf(lb - m);
    evs[(size_t)i * C + c] = ea + eb;

    // label diff per class (bitwise identical to reference f32 math)
    const float2 lc = ((const float2*)labels)[c];
    const float2 li = ((const float2*)labels)[i & 255];
    ld2[(size_t)i * C + c] = fabsf(li.x - lc.x) + fabsf(li.y - lc.y);

    // rowsum = sum_{k != i}(lg_k - m) = (sum_k lg_k) - 511*m   (lg_i == 0)
    float s = la + lb;
    __shared__ float reds[4];
#pragma unroll
    for (int off = 32; off > 0; off >>= 1) s += __shfl_xor(s, off, 64);
    if ((c & 63) == 0) reds[c >> 6] = s;
    __syncthreads();
    if (c == 0) rowsum[i] = (reds[0] + reds[1] + reds[2] + reds[3]) - 511.f * m;
}

// ---------------- K3: class denominators + per-row loss ----------------
// Inner loop reads provably wave-uniform scalar floats from arrays written by a
// DIFFERENT kernel -> compiler emits s_load (scalar cache), leaving only
// 3 VALU (v_cmp + v_add + v_cndmask) per element.
__global__ __launch_bounds__(256) void k3_den(const float* __restrict__ ld2,
                                              const float* __restrict__ evs,
                                              const float* __restrict__ rowsum,
                                              float* __restrict__ rowout) {
    const int i = blockIdx.x;
    const int c = threadIdx.x;
    const float* __restrict__ rl = ld2 + (size_t)i * C;
    const float* __restrict__ re = evs + (size_t)i * C;
    const float ldk = rl[c];

    float d0 = 0.f, d1 = 0.f, d2 = 0.f, d3 = 0.f;
#pragma unroll 8
    for (int q = 0; q < C; q += 4) {
        float a0 = rl[q + 0], a1 = rl[q + 1], a2 = rl[q + 2], a3 = rl[q + 3];
        float b0 = re[q + 0], b1 = re[q + 1], b2 = re[q + 2], b3 = re[q + 3];
        d0 += (a0 >= ldk) ? b0 : 0.f;
        d1 += (a1 >= ldk) ? b1 : 0.f;
        d2 += (a2 >= ldk) ? b2 : 0.f;
        d3 += (a3 >= ldk) ? b3 : 0.f;
    }
    const float lden = __logf((d0 + d1) + (d2 + d3));

    // rowout[i] = rowsum[i] - (2*sum_c log den_c - log den_{class(i)})
    __shared__ float red[4];
    __shared__ float lci;
    if (c == (i & 255)) lci = lden;   // class(i): ld == 0 -> den == total sum
    float s = lden;
#pragma unroll
    for (int off = 32; off > 0; off >>= 1) s += __shfl_xor(s, off, 64);
    if ((c & 63) == 0) red[c >> 6] = s;
    __syncthreads();
    if (c == 0) {
        float tot = red[0] + red[1] + red[2] + red[3];
        rowout[i] = rowsum[i] - (2.f * tot - lci);
    }
}

// ---------------- K4: final reduction ----------------
__global__ __launch_bounds__(256) void k4_reduce(const float* __restrict__ rowout,
                                                 float* __restrict__ out) {
    const int tid = threadIdx.x;
    double s = 0.0;
    for (int j = tid; j < N; j += 256) s += (double)rowout[j];
#pragma unroll
    for (int off = 32; off > 0; off >>= 1) s += __shfl_down(s, off, 64);
    __shared__ double sd[4];
    if ((tid & 63) == 0) sd[tid >> 6] = s;
    __syncthreads();
    if (tid == 0) {
        double t = sd[0] + sd[1] + sd[2] + sd[3];
        out[0] = (float)(-t / ((double)N * (double)(N - 1)));
    }
}

extern "C" void kernel_launch(void* const* d_in, const int* in_sizes, int n_in,
                              void* d_out, int out_size, void* d_ws, size_t ws_size,
                              hipStream_t stream) {
    const float* feat   = (const float*)d_in[0];   // [512,128] f32
    const float* labels = (const float*)d_in[1];   // [256,2]  f32
    float* out = (float*)d_out;

    float* lg     = (float*)d_ws;                  // N*N
    float* ld2    = lg + (size_t)N * N;            // N*C
    float* evs    = ld2 + (size_t)N * C;           // N*C
    float* rowsum = evs + (size_t)N * C;           // N
    float* rowout = rowsum + N;                    // N

    k1_logits<<<256, 256, 0, stream>>>(feat, lg);
    k2_row  <<<N,   256, 0, stream>>>(lg, labels, ld2, evs, rowsum);
    k3_den  <<<N,   256, 0, stream>>>(ld2, evs, rowsum, rowout);
    k4_reduce<<<1,  256, 0, stream>>>(rowout, out);
}